// Round 4
// baseline (169.201 us; speedup 1.0000x reference)
//
#include <hip/hip_runtime.h>

// ConvT3d(32->16,k3,s2,p1)+BN+4^3 avgpool, bf16 MFMA, 4096-block grid.
// R9: wT -> LDS. Theory: each wave streamed all 27.6KB of wT from global
// (27 x 1KB b128 loads = 452MB logical across grid) while x-staging (37KB/
// block) churned the 32KB L1 -> B-loads were ~300cyc L2 hits, ~8k exposed
// cyc/wave, the dominant stall. Now wTs[13824] lives in LDS (staged with 7
// uint4 loads/thread merged into the SAME vmcnt window as the 9 x float4
// loads -> still one round-trip); all B reads become conflict-free
// ds_read_b128. LDS total 48.2KB -> still 3 blocks/CU (= observed occ).
// launch_bounds (256,3): LDS caps at 3 blocks, give regalloc the 170 budget.
// Staging transpose (R8), parity decomposition (validated R1-R8):
//   even o: k=1,i=o/2; odd o=2m+1: k=0 -> i=m+1 ; k=2 -> i=m.
// kh-pair table: kh0: (hi1,oh1),(hi2,oh3); kh1: (hi0,oh0),(hi1,oh2);
//                kh2: (hi0,oh1),(hi1,oh3)

typedef __attribute__((ext_vector_type(8))) short bf16x8;
typedef __attribute__((ext_vector_type(4))) float f32x4;

static __device__ __forceinline__ unsigned short f2bf(float f) {
    unsigned int u = __float_as_uint(f);
    u = (u + 0x7fffu + ((u >> 16) & 1u)) >> 16;   // RNE
    return (unsigned short)u;
}
// RNE pack of 2 f32 -> 2 bf16 in one instr (identical rounding to f2bf)
static __device__ __forceinline__ unsigned cvtpk(float a, float b) {
    unsigned r;
    asm("v_cvt_pk_bf16_f32 %0, %1, %2" : "=v"(r) : "v"(a), "v"(b));
    return r;
}

// ---- w convert: w[ci][co][tap] fp32 -> wT[tap][co][ci] bf16 (tap=kd*9+kh*3+kw)
__global__ __launch_bounds__(256)
void kw(const float* __restrict__ w, unsigned short* __restrict__ wT)
{
    const int idx = blockIdx.x * 256 + threadIdx.x;
    if (idx < 13824) {
        const int ci = idx & 31, co = (idx >> 5) & 15, tap = idx >> 9;
        wT[idx] = f2bf(w[(ci * 16 + co) * 27 + tap]);
    }
}

// ---- fused stage + convT + BN-stats + pool partials
__global__ __launch_bounds__(256, 3)
void convf2(const float* __restrict__ x,
            const unsigned short* __restrict__ wT,
            const float* __restrict__ bias,
            float* __restrict__ pooled,
            float* __restrict__ psum, float* __restrict__ psq)
{
    const int ht = blockIdx.x, dt = blockIdx.y, n = blockIdx.z;
    const int tid = threadIdx.x;
    const int v = tid >> 6, lane = tid & 63;
    const int t = v & 1, odp = v >> 1;          // ow 16-tile, od pair
    const int c = lane & 15, qd = lane >> 4;    // co / A-row m, K-granule

    // xs[dihi(9)][g(4)][iw(33)][o(8)] bf16 = 19008 B
    __shared__ alignas(16) unsigned short xs[9504];
    // wTs[tap(27)][co(16)][ci(32)] bf16 = 27648 B
    __shared__ alignas(16) unsigned short wTs[13824];
    __shared__ float sred[4][16], qred[4][16], pbuf[2][8][16];

    const float bv = bias[c];   // hoisted: hides epilogue load latency

    // ---- stage: issue x loads (9 x float4) AND wT loads (7 x uint4) in one
    // vmcnt window -> single latency round-trip for the whole staging phase.
    const int ciS = tid >> 3, q = tid & 7;
    const int oL = ciS & 7;                     // = lane bits 3..5
    const float* xbase = x + (n*32 + ciS)*32768 + 4*q;
    float4 F[9];
    #pragma unroll
    for (int p = 0; p < 9; ++p) {
        const int di = p / 3, hi = p - 3*(p/3);
        const int id = 2*dt + di, ih = 2*ht + hi;
        const bool ok = (id < 32) && (ih < 32);   // block-uniform
        F[p] = ok ? *(const float4*)(xbase + id*1024 + ih*32)
                  : make_float4(0.f, 0.f, 0.f, 0.f);
    }
    uint4 Wv[7];
    #pragma unroll
    for (int k = 0; k < 7; ++k) {
        const int idx = tid + 256*k;            // 1728 uint4 total
        if (idx < 1728) Wv[k] = ((const uint4*)wT)[idx];
    }

    // in-register transpose 4iw x 8ci -> [iw][o] packs, per plane:
    //  round A (lane^8, 16-bit half <-> iw bit0) via v_perm
    //  round B (lane^16, reg <-> iw bit1) via select
    const unsigned selP = (lane & 8) ? 0x07060302u : 0x01000504u;
    const int iwT = 4*q + (oL & 3), hT = oL >> 2;
    #pragma unroll
    for (int p = 0; p < 9; ++p) {
        unsigned u0 = cvtpk(F[p].x, F[p].y);
        unsigned u1 = cvtpk(F[p].z, F[p].w);
        const unsigned a0 = (unsigned)__shfl_xor((int)u0, 8, 64);
        const unsigned a1 = (unsigned)__shfl_xor((int)u1, 8, 64);
        u0 = __builtin_amdgcn_perm(u0, a0, selP);
        u1 = __builtin_amdgcn_perm(u1, a1, selP);
        const unsigned t0 = (unsigned)__shfl_xor((int)u0, 16, 64);
        const unsigned t1 = (unsigned)__shfl_xor((int)u1, 16, 64);
        const unsigned n0 = (lane & 16) ? t1 : u0;
        const unsigned n1 = (lane & 16) ? u1 : t0;
        *(uint2*)(xs + p*1056 + v*264 + iwT*8 + 4*hT) = make_uint2(n0, n1);
    }
    #pragma unroll
    for (int k = 0; k < 7; ++k) {
        const int idx = tid + 256*k;
        if (idx < 1728) *(uint4*)(wTs + idx*8) = Wv[k];
    }
    if (tid < 36) {
        const int dihi = tid >> 2, gg = tid & 3;
        *(uint4*)(xs + dihi*1056 + gg*264 + 256) = make_uint4(0,0,0,0);
    }

    __syncthreads();

    f32x4 acc[2][4][2];   // [ol][oh][par]
    #pragma unroll
    for (int ol = 0; ol < 2; ++ol)
        #pragma unroll
        for (int oh = 0; oh < 4; ++oh)
            #pragma unroll
            for (int par = 0; par < 2; ++par)
                acc[ol][oh][par] = (f32x4){0.f,0.f,0.f,0.f};

    const int iwb = 16 * t + c;
    auto LDA = [&](int dihi, int sofs) -> bf16x8 {
        return *(const bf16x8*)(xs + dihi*1056 + qd*264 + (iwb + sofs)*8);
    };
    auto LDB = [&](int tap) -> bf16x8 {           // LDS, conflict-free b128
        return *(const bf16x8*)(wTs + tap*512 + c*32 + qd*8);
    };

    // kh-outer pair table: [kh][pair] -> (hi, oh)
    constexpr int KHP[3][2][2] = {
        {{1,1},{2,3}},   // kh0
        {{0,0},{1,2}},   // kh1
        {{0,1},{1,3}},   // kh2
    };
    const int PB[3]  = {9, 18, 0};       // tap base per phase (kd=1,2,0)
    const int POL[3] = {0, 1, 1};        // ol per phase
    const int PDI[3] = {odp, odp, odp + 1};

    bf16x8 B0 = LDB(9 + 0), B1 = LDB(9 + 1), B2 = LDB(9 + 2);
    #pragma unroll
    for (int s = 0; s < 9; ++s) {
        const int ph = s / 3;
        bf16x8 N0, N1, N2;
        if (s < 8) {                      // prefetch next kh-group (LDS)
            const int sn = s + 1;
            const int phn = sn / 3, khn = sn - 3*(sn/3);
            const int bn_ = PB[phn] + khn * 3;
            N0 = LDB(bn_ + 0); N1 = LDB(bn_ + 1); N2 = LDB(bn_ + 2);
        }
        const int kh = s - 3*(s/3);
        const int ol = POL[ph], di = PDI[ph];
        #pragma unroll
        for (int pp = 0; pp < 2; ++pp) {
            const int hi = KHP[kh][pp][0], oh = KHP[kh][pp][1];
            const bf16x8 A0 = LDA(di*3 + hi, 0), A1 = LDA(di*3 + hi, 1);
            acc[ol][oh][0] = __builtin_amdgcn_mfma_f32_16x16x32_bf16(
                A0, B1, acc[ol][oh][0], 0, 0, 0);
            acc[ol][oh][1] = __builtin_amdgcn_mfma_f32_16x16x32_bf16(
                A1, B0, acc[ol][oh][1], 0, 0, 0);
            acc[ol][oh][1] = __builtin_amdgcn_mfma_f32_16x16x32_bf16(
                A0, B2, acc[ol][oh][1], 0, 0, 0);
        }
        if (s < 8) { B0 = N0; B1 = N1; B2 = N2; }
    }

    // ---- epilogue: bias, BN stats (masked), pool partials (validated R2-R8)
    float s = 0.f, sq = 0.f;
    float P[2] = {0.f, 0.f};
    #pragma unroll
    for (int ol = 0; ol < 2; ++ol) {
        const int odg = 2*odp + ol;
        const bool odok = !(dt == 15 && odg == 3);
        #pragma unroll
        for (int oh = 0; oh < 4; ++oh) {
            const bool ohok = !(ht == 15 && oh == 3);
            #pragma unroll
            for (int par = 0; par < 2; ++par)
                #pragma unroll
                for (int r = 0; r < 4; ++r) {
                    const float val = acc[ol][oh][par][r] + bv;
                    const bool owok = !(par == 1 && t == 1 && qd == 3 && r == 3);
                    const float mk = (odok && ohok && owok) ? 1.f : 0.f;
                    s += mk * val; sq += mk * val * val;
                    P[r >> 1] += val;
                }
        }
    }
    s  += __shfl_xor(s, 16, 64);  s  += __shfl_xor(s, 32, 64);
    sq += __shfl_xor(sq, 16, 64); sq += __shfl_xor(sq, 32, 64);

    if (lane < 16) { sred[v][lane] = s; qred[v][lane] = sq; }
    if (odp == 0 && dt < 15 && ht < 15) {
        pbuf[t][2*qd + 0][c] = P[0];
        pbuf[t][2*qd + 1][c] = P[1];
    }
    __syncthreads();
    if (tid < 16) {
        const int blk = (n*16 + dt)*16 + ht;
        psum[tid*4096 + blk] = sred[0][tid]+sred[1][tid]+sred[2][tid]+sred[3][tid];
        psq [tid*4096 + blk] = qred[0][tid]+qred[1][tid]+qred[2][tid]+qred[3][tid];
    }
    if (odp == 1 && dt < 15 && ht < 15) {
        #pragma unroll
        for (int jj = 0; jj < 2; ++jj) {
            const int jl = 2*qd + jj, jg = 8*t + jl;
            if (jg < 15) {
                const float tot = pbuf[t][jl][c] + P[jj];
                pooled[(n*16 + c)*3375 + dt*225 + ht*15 + jg] = tot * (1.f/64.f);
            }
        }
    }
}

__global__ void bnfinal(const float* __restrict__ psum, const float* __restrict__ psq,
                        const float* __restrict__ gamma, const float* __restrict__ beta,
                        float* __restrict__ bn)
{
    const int co = blockIdx.x;
    const int t  = threadIdx.x;
    float S = 0, Q = 0;
    for (int blk = t; blk < 4096; blk += 256) {
        S += psum[co*4096 + blk];
        Q += psq [co*4096 + blk];
    }
    #pragma unroll
    for (int off = 32; off > 0; off >>= 1) {
        S += __shfl_down(S, off, 64);
        Q += __shfl_down(Q, off, 64);
    }
    __shared__ float rs[4], rq[4];
    if ((t & 63) == 0) { rs[t >> 6] = S; rq[t >> 6] = Q; }
    __syncthreads();
    if (t == 0) {
        S = rs[0] + rs[1] + rs[2] + rs[3];
        Q = rq[0] + rq[1] + rq[2] + rq[3];
        const float cnt = 16.f * 63.f * 63.f * 63.f;
        const float mean = S / cnt;
        const float var  = Q / cnt - mean * mean;
        const float inv  = rsqrtf(var + 1e-5f);
        const float sc   = inv * gamma[co];
        bn[co]      = sc;
        bn[16 + co] = beta[co] - mean * sc;
    }
}

__global__ void finalize(const float* __restrict__ pooled, const float* __restrict__ bn,
                         float* __restrict__ out)
{
    const int i  = blockIdx.x * 256 + threadIdx.x;   // 864000 = 3375*256
    const int co = (i / 3375) & 15;
    out[i] = pooled[i] * bn[co] + bn[16 + co];
}

extern "C" void kernel_launch(void* const* d_in, const int* in_sizes, int n_in,
                              void* d_out, int out_size, void* d_ws, size_t ws_size,
                              hipStream_t stream)
{
    const float* x     = (const float*)d_in[0];
    const float* w     = (const float*)d_in[1];
    const float* b     = (const float*)d_in[2];
    const float* gamma = (const float*)d_in[3];
    const float* beta  = (const float*)d_in[4];
    float* out = (float*)d_out;

    char* wsb = (char*)d_ws;
    unsigned short* wT = (unsigned short*)wsb;        // 27,648 B
    float* pooled = (float*)(wsb + 27648);            // 3,456,000 B
    float* psum   = (float*)(wsb + 27648 + 3456000);  // 262,144 B
    float* psq    = (float*)(wsb + 27648 + 3456000 + 262144);
    float* bn     = (float*)(wsb + 27648 + 3456000 + 2*262144);

    kw<<<54, 256, 0, stream>>>(w, wT);
    dim3 grid(16, 16, 16);   // (ht, dt, n)
    convf2<<<grid, 256, 0, stream>>>(x, wT, b, pooled, psum, psq);
    bnfinal<<<16, 256, 0, stream>>>(psum, psq, gamma, beta, bn);
    finalize<<<3375, 256, 0, stream>>>(pooled, bn, out);
}

// Round 5
// 131.918 us; speedup vs baseline: 1.2826x; 1.2826x over previous
//
#include <hip/hip_runtime.h>

// ConvT3d(32->16,k3,s2,p1)+BN+4^3 avgpool, bf16 MFMA, 4096-block grid.
// R10: wT -> LDS via __builtin_amdgcn_global_load_lds (ZERO VGPR staging).
// R9 failed because register-staged wT (Wv[7]+F[9] live together) spilled to
// scratch: WRITE_SIZE 9->119MB = 4096x256x112B. global_load_lds writes
// LDS at wave-uniform base + lane*16 with per-lane global src -> a linear
// wTs copy matches exactly (27 x 1KB chunks, ~7/wave). Issued before the x
// loads; __syncthreads' vmcnt(0) drain completes them.
// Rest = proven R8 structure: 9 x float4 x-staging + in-reg transpose
// (cvt_pk -> shfl_xor8+v_perm -> shfl_xor16+select), B-prefetch (3 frags
// ahead) now from LDS (b128, 2-way banks = free), launch_bounds(256,4).
// LDS 48.2KB -> 3 blocks/CU (= current occupancy).
// Parity decomposition (validated R1-R9): even o: k=1,i=o/2;
//   odd o=2m+1: k=0 -> i=m+1 ; k=2 -> i=m.
// kh-pair table: kh0: (hi1,oh1),(hi2,oh3); kh1: (hi0,oh0),(hi1,oh2);
//                kh2: (hi0,oh1),(hi1,oh3)

typedef __attribute__((ext_vector_type(8))) short bf16x8;
typedef __attribute__((ext_vector_type(4))) float f32x4;

static __device__ __forceinline__ unsigned short f2bf(float f) {
    unsigned int u = __float_as_uint(f);
    u = (u + 0x7fffu + ((u >> 16) & 1u)) >> 16;   // RNE
    return (unsigned short)u;
}
// RNE pack of 2 f32 -> 2 bf16 in one instr (identical rounding to f2bf)
static __device__ __forceinline__ unsigned cvtpk(float a, float b) {
    unsigned r;
    asm("v_cvt_pk_bf16_f32 %0, %1, %2" : "=v"(r) : "v"(a), "v"(b));
    return r;
}

// ---- w convert: w[ci][co][tap] fp32 -> wT[tap][co][ci] bf16 (tap=kd*9+kh*3+kw)
__global__ __launch_bounds__(256)
void kw(const float* __restrict__ w, unsigned short* __restrict__ wT)
{
    const int idx = blockIdx.x * 256 + threadIdx.x;
    if (idx < 13824) {
        const int ci = idx & 31, co = (idx >> 5) & 15, tap = idx >> 9;
        wT[idx] = f2bf(w[(ci * 16 + co) * 27 + tap]);
    }
}

// ---- fused stage + convT + BN-stats + pool partials
__global__ __launch_bounds__(256, 4)
void convf2(const float* __restrict__ x,
            const unsigned short* __restrict__ wT,
            const float* __restrict__ bias,
            float* __restrict__ pooled,
            float* __restrict__ psum, float* __restrict__ psq)
{
    const int ht = blockIdx.x, dt = blockIdx.y, n = blockIdx.z;
    const int tid = threadIdx.x;
    const int v = tid >> 6, lane = tid & 63;
    const int t = v & 1, odp = v >> 1;          // ow 16-tile, od pair
    const int c = lane & 15, qd = lane >> 4;    // co / A-row m, K-granule

    // xs[dihi(9)][g(4)][iw(33)][o(8)] bf16 = 19008 B
    __shared__ alignas(16) unsigned short xs[9504];
    // wTs = linear copy of wT: [tap(27)][co(16)][ci(32)] bf16 = 27648 B
    __shared__ alignas(16) unsigned short wTs[13824];
    __shared__ float sred[4][16], qred[4][16], pbuf[2][8][16];

    const float bv = bias[c];   // hoisted: hides epilogue load latency

    // ---- stage wT -> LDS, zero VGPR: 27 x 1KB chunks, wave-uniform branch.
    #pragma unroll
    for (int i = 0; i < 7; ++i) {
        const int chunk = v + 4 * i;            // wave-uniform
        if (chunk < 27) {
            __builtin_amdgcn_global_load_lds(
                (const char*)wT + chunk * 1024 + lane * 16,
                (char*)wTs + chunk * 1024,
                16, 0, 0);
        }
    }

    // ---- stage x: wide loads. thread = (ci = tid>>3, iw-quad q = tid&7).
    const int ciS = tid >> 3, q = tid & 7;
    const int oL = ciS & 7;                     // = lane bits 3..5
    const float* xbase = x + (n*32 + ciS)*32768 + 4*q;
    float4 F[9];
    #pragma unroll
    for (int p = 0; p < 9; ++p) {
        const int di = p / 3, hi = p - 3*(p/3);
        const int id = 2*dt + di, ih = 2*ht + hi;
        const bool ok = (id < 32) && (ih < 32);   // block-uniform
        F[p] = ok ? *(const float4*)(xbase + id*1024 + ih*32)
                  : make_float4(0.f, 0.f, 0.f, 0.f);
    }

    // in-register transpose 4iw x 8ci -> [iw][o] packs, per plane:
    //  round A (lane^8, 16-bit half <-> iw bit0) via v_perm
    //  round B (lane^16, reg <-> iw bit1) via select
    const unsigned selP = (lane & 8) ? 0x07060302u : 0x01000504u;
    const int iwT = 4*q + (oL & 3), hT = oL >> 2;
    #pragma unroll
    for (int p = 0; p < 9; ++p) {
        unsigned u0 = cvtpk(F[p].x, F[p].y);
        unsigned u1 = cvtpk(F[p].z, F[p].w);
        const unsigned a0 = (unsigned)__shfl_xor((int)u0, 8, 64);
        const unsigned a1 = (unsigned)__shfl_xor((int)u1, 8, 64);
        u0 = __builtin_amdgcn_perm(u0, a0, selP);
        u1 = __builtin_amdgcn_perm(u1, a1, selP);
        const unsigned t0 = (unsigned)__shfl_xor((int)u0, 16, 64);
        const unsigned t1 = (unsigned)__shfl_xor((int)u1, 16, 64);
        const unsigned n0 = (lane & 16) ? t1 : u0;
        const unsigned n1 = (lane & 16) ? u1 : t0;
        *(uint2*)(xs + p*1056 + v*264 + iwT*8 + 4*hT) = make_uint2(n0, n1);
    }
    if (tid < 36) {
        const int dihi = tid >> 2, gg = tid & 3;
        *(uint4*)(xs + dihi*1056 + gg*264 + 256) = make_uint4(0,0,0,0);
    }

    __syncthreads();   // drains vmcnt(0) -> global_load_lds complete

    f32x4 acc[2][4][2];   // [ol][oh][par]
    #pragma unroll
    for (int ol = 0; ol < 2; ++ol)
        #pragma unroll
        for (int oh = 0; oh < 4; ++oh)
            #pragma unroll
            for (int par = 0; par < 2; ++par)
                acc[ol][oh][par] = (f32x4){0.f,0.f,0.f,0.f};

    const int iwb = 16 * t + c;
    auto LDA = [&](int dihi, int sofs) -> bf16x8 {
        return *(const bf16x8*)(xs + dihi*1056 + qd*264 + (iwb + sofs)*8);
    };
    auto LDB = [&](int tap) -> bf16x8 {           // LDS b128, 2-way = free
        return *(const bf16x8*)(wTs + tap*512 + c*32 + qd*8);
    };

    // kh-outer pair table: [kh][pair] -> (hi, oh)
    constexpr int KHP[3][2][2] = {
        {{1,1},{2,3}},   // kh0
        {{0,0},{1,2}},   // kh1
        {{0,1},{1,3}},   // kh2
    };
    const int PB[3]  = {9, 18, 0};       // tap base per phase (kd=1,2,0)
    const int POL[3] = {0, 1, 1};        // ol per phase
    const int PDI[3] = {odp, odp, odp + 1};

    bf16x8 B0 = LDB(9 + 0), B1 = LDB(9 + 1), B2 = LDB(9 + 2);
    #pragma unroll
    for (int s = 0; s < 9; ++s) {
        const int ph = s / 3;
        bf16x8 N0, N1, N2;
        if (s < 8) {                      // prefetch next kh-group (LDS)
            const int sn = s + 1;
            const int phn = sn / 3, khn = sn - 3*(sn/3);
            const int bn_ = PB[phn] + khn * 3;
            N0 = LDB(bn_ + 0); N1 = LDB(bn_ + 1); N2 = LDB(bn_ + 2);
        }
        const int kh = s - 3*(s/3);
        const int ol = POL[ph], di = PDI[ph];
        #pragma unroll
        for (int pp = 0; pp < 2; ++pp) {
            const int hi = KHP[kh][pp][0], oh = KHP[kh][pp][1];
            const bf16x8 A0 = LDA(di*3 + hi, 0), A1 = LDA(di*3 + hi, 1);
            acc[ol][oh][0] = __builtin_amdgcn_mfma_f32_16x16x32_bf16(
                A0, B1, acc[ol][oh][0], 0, 0, 0);
            acc[ol][oh][1] = __builtin_amdgcn_mfma_f32_16x16x32_bf16(
                A1, B0, acc[ol][oh][1], 0, 0, 0);
            acc[ol][oh][1] = __builtin_amdgcn_mfma_f32_16x16x32_bf16(
                A0, B2, acc[ol][oh][1], 0, 0, 0);
        }
        if (s < 8) { B0 = N0; B1 = N1; B2 = N2; }
    }

    // ---- epilogue: bias, BN stats (masked), pool partials (validated R2-R9)
    float s = 0.f, sq = 0.f;
    float P[2] = {0.f, 0.f};
    #pragma unroll
    for (int ol = 0; ol < 2; ++ol) {
        const int odg = 2*odp + ol;
        const bool odok = !(dt == 15 && odg == 3);
        #pragma unroll
        for (int oh = 0; oh < 4; ++oh) {
            const bool ohok = !(ht == 15 && oh == 3);
            #pragma unroll
            for (int par = 0; par < 2; ++par)
                #pragma unroll
                for (int r = 0; r < 4; ++r) {
                    const float val = acc[ol][oh][par][r] + bv;
                    const bool owok = !(par == 1 && t == 1 && qd == 3 && r == 3);
                    const float mk = (odok && ohok && owok) ? 1.f : 0.f;
                    s += mk * val; sq += mk * val * val;
                    P[r >> 1] += val;
                }
        }
    }
    s  += __shfl_xor(s, 16, 64);  s  += __shfl_xor(s, 32, 64);
    sq += __shfl_xor(sq, 16, 64); sq += __shfl_xor(sq, 32, 64);

    if (lane < 16) { sred[v][lane] = s; qred[v][lane] = sq; }
    if (odp == 0 && dt < 15 && ht < 15) {
        pbuf[t][2*qd + 0][c] = P[0];
        pbuf[t][2*qd + 1][c] = P[1];
    }
    __syncthreads();
    if (tid < 16) {
        const int blk = (n*16 + dt)*16 + ht;
        psum[tid*4096 + blk] = sred[0][tid]+sred[1][tid]+sred[2][tid]+sred[3][tid];
        psq [tid*4096 + blk] = qred[0][tid]+qred[1][tid]+qred[2][tid]+qred[3][tid];
    }
    if (odp == 1 && dt < 15 && ht < 15) {
        #pragma unroll
        for (int jj = 0; jj < 2; ++jj) {
            const int jl = 2*qd + jj, jg = 8*t + jl;
            if (jg < 15) {
                const float tot = pbuf[t][jl][c] + P[jj];
                pooled[(n*16 + c)*3375 + dt*225 + ht*15 + jg] = tot * (1.f/64.f);
            }
        }
    }
}

__global__ void bnfinal(const float* __restrict__ psum, const float* __restrict__ psq,
                        const float* __restrict__ gamma, const float* __restrict__ beta,
                        float* __restrict__ bn)
{
    const int co = blockIdx.x;
    const int t  = threadIdx.x;
    float S = 0, Q = 0;
    for (int blk = t; blk < 4096; blk += 256) {
        S += psum[co*4096 + blk];
        Q += psq [co*4096 + blk];
    }
    #pragma unroll
    for (int off = 32; off > 0; off >>= 1) {
        S += __shfl_down(S, off, 64);
        Q += __shfl_down(Q, off, 64);
    }
    __shared__ float rs[4], rq[4];
    if ((t & 63) == 0) { rs[t >> 6] = S; rq[t >> 6] = Q; }
    __syncthreads();
    if (t == 0) {
        S = rs[0] + rs[1] + rs[2] + rs[3];
        Q = rq[0] + rq[1] + rq[2] + rq[3];
        const float cnt = 16.f * 63.f * 63.f * 63.f;
        const float mean = S / cnt;
        const float var  = Q / cnt - mean * mean;
        const float inv  = rsqrtf(var + 1e-5f);
        const float sc   = inv * gamma[co];
        bn[co]      = sc;
        bn[16 + co] = beta[co] - mean * sc;
    }
}

__global__ void finalize(const float* __restrict__ pooled, const float* __restrict__ bn,
                         float* __restrict__ out)
{
    const int i  = blockIdx.x * 256 + threadIdx.x;   // 864000 = 3375*256
    const int co = (i / 3375) & 15;
    out[i] = pooled[i] * bn[co] + bn[16 + co];
}

extern "C" void kernel_launch(void* const* d_in, const int* in_sizes, int n_in,
                              void* d_out, int out_size, void* d_ws, size_t ws_size,
                              hipStream_t stream)
{
    const float* x     = (const float*)d_in[0];
    const float* w     = (const float*)d_in[1];
    const float* b     = (const float*)d_in[2];
    const float* gamma = (const float*)d_in[3];
    const float* beta  = (const float*)d_in[4];
    float* out = (float*)d_out;

    char* wsb = (char*)d_ws;
    unsigned short* wT = (unsigned short*)wsb;        // 27,648 B
    float* pooled = (float*)(wsb + 27648);            // 3,456,000 B
    float* psum   = (float*)(wsb + 27648 + 3456000);  // 262,144 B
    float* psq    = (float*)(wsb + 27648 + 3456000 + 262144);
    float* bn     = (float*)(wsb + 27648 + 3456000 + 2*262144);

    kw<<<54, 256, 0, stream>>>(w, wT);
    dim3 grid(16, 16, 16);   // (ht, dt, n)
    convf2<<<grid, 256, 0, stream>>>(x, wT, b, pooled, psum, psq);
    bnfinal<<<16, 256, 0, stream>>>(psum, psq, gamma, beta, bn);
    finalize<<<3375, 256, 0, stream>>>(pooled, bn, out);
}

// Round 6
// 128.294 us; speedup vs baseline: 1.3188x; 1.0282x over previous
//
#include <hip/hip_runtime.h>

// ConvT3d(32->16,k3,s2,p1)+BN+4^3 avgpool, bf16 MFMA.
// R11: 4 n-tiles per block, software-pipelined (grid 16x16x4 = 1024 blocks).
// Finding from R10 counters: ~86us of dur_us is harness fillBuffer re-poison
// (2 x 268MB @ 78% peak) + ~3us for kw/bnfinal/finalize; convf2 is the only
// lever. Its remaining stall = per-block cold staging round-trip + full wT
// re-stage, repeated 16x/CU with 2 resident. Now: wT staged ONCE per 4
// tiles (27 x global_load_lds, zero-VGPR); xs double-buffered; tile t+1's 9
// float4 x-loads issued before tile t's MFMAs (latency hidden under ~2000cyc
// compute); BN s/sq accumulated in regs across tiles (1 reduce); pooled
// writes deferred one tile via parity-indexed pbuf (barrier-safe).
// LDS 68.2KB -> 2 blocks/CU (= measured occupancy; nothing lost).
// launch_bounds(256,2): honest 256-reg budget; acc(64)+F(36)+B(24)+misc~150,
// F/Wv never coexist -> R9's spill mode impossible.
// Staging transpose (R8), parity decomposition (validated R1-R10):
//   even o: k=1,i=o/2; odd o=2m+1: k=0 -> i=m+1 ; k=2 -> i=m.
// kh-pair table: kh0: (hi1,oh1),(hi2,oh3); kh1: (hi0,oh0),(hi1,oh2);
//                kh2: (hi0,oh1),(hi1,oh3)

typedef __attribute__((ext_vector_type(8))) short bf16x8;
typedef __attribute__((ext_vector_type(4))) float f32x4;

static __device__ __forceinline__ unsigned short f2bf(float f) {
    unsigned int u = __float_as_uint(f);
    u = (u + 0x7fffu + ((u >> 16) & 1u)) >> 16;   // RNE
    return (unsigned short)u;
}
// RNE pack of 2 f32 -> 2 bf16 in one instr (identical rounding to f2bf)
static __device__ __forceinline__ unsigned cvtpk(float a, float b) {
    unsigned r;
    asm("v_cvt_pk_bf16_f32 %0, %1, %2" : "=v"(r) : "v"(a), "v"(b));
    return r;
}

// ---- w convert: w[ci][co][tap] fp32 -> wT[tap][co][ci] bf16 (tap=kd*9+kh*3+kw)
__global__ __launch_bounds__(256)
void kw(const float* __restrict__ w, unsigned short* __restrict__ wT)
{
    const int idx = blockIdx.x * 256 + threadIdx.x;
    if (idx < 13824) {
        const int ci = idx & 31, co = (idx >> 5) & 15, tap = idx >> 9;
        wT[idx] = f2bf(w[(ci * 16 + co) * 27 + tap]);
    }
}

// ---- fused stage + convT + BN-stats + pool partials, 4 n-tiles/block
__global__ __launch_bounds__(256, 2)
void convf2(const float* __restrict__ x,
            const unsigned short* __restrict__ wT,
            const float* __restrict__ bias,
            float* __restrict__ pooled,
            float* __restrict__ psum, float* __restrict__ psq)
{
    const int ht = blockIdx.x, dt = blockIdx.y, bz = blockIdx.z;
    const int n0 = bz * 4;
    const int tid = threadIdx.x;
    const int v = tid >> 6, lane = tid & 63;
    const int tw = v & 1, odp = v >> 1;         // ow 16-tile, od pair
    const int c = lane & 15, qd = lane >> 4;    // co / A-row m, K-granule

    // xs[buf][dihi(9)][g(4)][iw(33)][o(8)] bf16 = 2 x 19008 B
    __shared__ alignas(16) unsigned short xs[2][9504];
    // wTs = linear copy of wT: [tap(27)][co(16)][ci(32)] bf16 = 27648 B
    __shared__ alignas(16) unsigned short wTs[13824];
    __shared__ float sred[4][16], qred[4][16], pbuf[2][2][8][16];

    const float bv = bias[c];

    // ---- stage wT -> LDS once per block, zero VGPR (27 x 1KB chunks)
    #pragma unroll
    for (int i = 0; i < 7; ++i) {
        const int chunk = v + 4 * i;            // wave-uniform
        if (chunk < 27) {
            __builtin_amdgcn_global_load_lds(
                (const char*)wT + chunk * 1024 + lane * 16,
                (char*)wTs + chunk * 1024,
                16, 0, 0);
        }
    }

    // ---- x staging geometry (block-uniform plane offsets/masks)
    const int ciS = tid >> 3, q = tid & 7;
    const int oL = ciS & 7;                     // = lane bits 3..5
    int  offp[9]; bool okp[9];
    #pragma unroll
    for (int p = 0; p < 9; ++p) {
        const int di = p / 3, hi = p - 3*(p/3);
        const int id = 2*dt + di, ih = 2*ht + hi;
        okp[p]  = (id < 32) && (ih < 32);
        offp[p] = id*1024 + ih*32;
    }
    float4 F[9];
    auto ISSUE = [&](int nn) {
        const float* xb = x + (size_t)(nn*32 + ciS)*32768 + 4*q;
        #pragma unroll
        for (int p = 0; p < 9; ++p)
            F[p] = okp[p] ? *(const float4*)(xb + offp[p])
                          : make_float4(0.f, 0.f, 0.f, 0.f);
    };
    // in-register transpose 4iw x 8ci -> [iw][o] packs (validated R8-R10)
    const unsigned selP = (lane & 8) ? 0x07060302u : 0x01000504u;
    const int iwT = 4*q + (oL & 3), hT = oL >> 2;
    auto TRANSP = [&](int buf) {
        unsigned short* xp = &xs[buf][0];
        #pragma unroll
        for (int p = 0; p < 9; ++p) {
            unsigned u0 = cvtpk(F[p].x, F[p].y);
            unsigned u1 = cvtpk(F[p].z, F[p].w);
            const unsigned a0 = (unsigned)__shfl_xor((int)u0, 8, 64);
            const unsigned a1 = (unsigned)__shfl_xor((int)u1, 8, 64);
            u0 = __builtin_amdgcn_perm(u0, a0, selP);
            u1 = __builtin_amdgcn_perm(u1, a1, selP);
            const unsigned b0 = (unsigned)__shfl_xor((int)u0, 16, 64);
            const unsigned b1 = (unsigned)__shfl_xor((int)u1, 16, 64);
            const unsigned w0 = (lane & 16) ? b1 : u0;
            const unsigned w1 = (lane & 16) ? u1 : b0;
            *(uint2*)(xp + p*1056 + v*264 + iwT*8 + 4*hT) = make_uint2(w0, w1);
        }
    };

    // prologue: tile 0 staging + static zero columns (iw=32, both buffers)
    ISSUE(n0);
    if (tid < 36) {
        const int dihi = tid >> 2, gg = tid & 3;
        *(uint4*)(&xs[0][0] + dihi*1056 + gg*264 + 256) = make_uint4(0,0,0,0);
        *(uint4*)(&xs[1][0] + dihi*1056 + gg*264 + 256) = make_uint4(0,0,0,0);
    }
    TRANSP(0);
    __syncthreads();   // drains vmcnt -> wTs + xs[0] ready

    // kh-outer pair table: [kh][pair] -> (hi, oh)
    constexpr int KHP[3][2][2] = {
        {{1,1},{2,3}},   // kh0
        {{0,0},{1,2}},   // kh1
        {{0,1},{1,3}},   // kh2
    };
    const int PB[3]  = {9, 18, 0};       // tap base per phase (kd=1,2,0)
    const int POL[3] = {0, 1, 1};        // ol per phase
    const int PDI[3] = {odp, odp, odp + 1};
    const int iwb = 16 * tw + c;
    auto LDB = [&](int tap) -> bf16x8 {
        return *(const bf16x8*)(wTs + tap*512 + c*32 + qd*8);
    };
    const bool pok = (dt < 15) && (ht < 15);

    float sA = 0.f, sqA = 0.f;          // BN partials across 4 tiles
    float Pd[2] = {0.f, 0.f};           // deferred pool (odp==1 waves)

    auto POOLW = [&](int t) {           // deferred pooled write for tile t
        if (odp == 1 && pok) {
            #pragma unroll
            for (int jj = 0; jj < 2; ++jj) {
                const int jl = 2*qd + jj, jg = 8*tw + jl;
                if (jg < 15) {
                    const float tot = pbuf[t & 1][tw][jl][c] + Pd[jj];
                    pooled[((n0 + t)*16 + c)*3375 + dt*225 + ht*15 + jg]
                        = tot * (1.f/64.f);
                }
            }
        }
    };

    for (int tt = 0; tt < 4; ++tt) {
        const int cur = tt & 1;
        if (tt < 3) ISSUE(n0 + tt + 1);          // prefetch next tile's x
        if (tt > 0) POOLW(tt - 1);               // deferred pool write

        const unsigned short* xcur = &xs[cur][0];
        auto LDA = [&](int dihi, int sofs) -> bf16x8 {
            return *(const bf16x8*)(xcur + dihi*1056 + qd*264 + (iwb + sofs)*8);
        };

        f32x4 acc[2][4][2];   // [ol][oh][par]
        #pragma unroll
        for (int ol = 0; ol < 2; ++ol)
            #pragma unroll
            for (int oh = 0; oh < 4; ++oh)
                #pragma unroll
                for (int par = 0; par < 2; ++par)
                    acc[ol][oh][par] = (f32x4){0.f,0.f,0.f,0.f};

        bf16x8 B0 = LDB(9 + 0), B1 = LDB(9 + 1), B2 = LDB(9 + 2);
        #pragma unroll
        for (int s = 0; s < 9; ++s) {
            const int ph = s / 3;
            bf16x8 N0, N1, N2;
            if (s < 8) {                  // prefetch next kh-group (LDS)
                const int sn = s + 1;
                const int phn = sn / 3, khn = sn - 3*(sn/3);
                const int bn_ = PB[phn] + khn * 3;
                N0 = LDB(bn_ + 0); N1 = LDB(bn_ + 1); N2 = LDB(bn_ + 2);
            }
            const int kh = s - 3*(s/3);
            const int ol = POL[ph], di = PDI[ph];
            #pragma unroll
            for (int pp = 0; pp < 2; ++pp) {
                const int hi = KHP[kh][pp][0], oh = KHP[kh][pp][1];
                const bf16x8 A0 = LDA(di*3 + hi, 0), A1 = LDA(di*3 + hi, 1);
                acc[ol][oh][0] = __builtin_amdgcn_mfma_f32_16x16x32_bf16(
                    A0, B1, acc[ol][oh][0], 0, 0, 0);
                acc[ol][oh][1] = __builtin_amdgcn_mfma_f32_16x16x32_bf16(
                    A1, B0, acc[ol][oh][1], 0, 0, 0);
                acc[ol][oh][1] = __builtin_amdgcn_mfma_f32_16x16x32_bf16(
                    A0, B2, acc[ol][oh][1], 0, 0, 0);
            }
            if (s < 8) { B0 = N0; B1 = N1; B2 = N2; }
        }

        // epilogue: bias, BN stats (masked), pool partials (validated R2-R10)
        float P[2] = {0.f, 0.f};
        #pragma unroll
        for (int ol = 0; ol < 2; ++ol) {
            const int odg = 2*odp + ol;
            const bool odok = !(dt == 15 && odg == 3);
            #pragma unroll
            for (int oh = 0; oh < 4; ++oh) {
                const bool ohok = !(ht == 15 && oh == 3);
                #pragma unroll
                for (int par = 0; par < 2; ++par)
                    #pragma unroll
                    for (int r = 0; r < 4; ++r) {
                        const float val = acc[ol][oh][par][r] + bv;
                        const bool owok = !(par == 1 && tw == 1 && qd == 3 && r == 3);
                        const float mk = (odok && ohok && owok) ? 1.f : 0.f;
                        sA += mk * val; sqA += mk * val * val;
                        P[r >> 1] += val;
                    }
            }
        }
        if (odp == 0 && pok) {
            pbuf[cur][tw][2*qd + 0][c] = P[0];
            pbuf[cur][tw][2*qd + 1][c] = P[1];
        } else {
            Pd[0] = P[0]; Pd[1] = P[1];
        }

        if (tt < 3) TRANSP(cur ^ 1);             // write next tile's xs
        __syncthreads();                         // xs swap + pbuf publish
    }

    POOLW(3);

    // single BN reduction for all 4 tiles
    sA  += __shfl_xor(sA, 16, 64);  sA  += __shfl_xor(sA, 32, 64);
    sqA += __shfl_xor(sqA, 16, 64); sqA += __shfl_xor(sqA, 32, 64);
    if (lane < 16) { sred[v][lane] = sA; qred[v][lane] = sqA; }
    __syncthreads();
    if (tid < 16) {
        const int blk = (bz*16 + dt)*16 + ht;    // [0,1024)
        psum[tid*4096 + blk] = sred[0][tid]+sred[1][tid]+sred[2][tid]+sred[3][tid];
        psq [tid*4096 + blk] = qred[0][tid]+qred[1][tid]+qred[2][tid]+qred[3][tid];
    }
}

__global__ void bnfinal(const float* __restrict__ psum, const float* __restrict__ psq,
                        const float* __restrict__ gamma, const float* __restrict__ beta,
                        float* __restrict__ bn)
{
    const int co = blockIdx.x;
    const int t  = threadIdx.x;
    float S = 0, Q = 0;
    for (int blk = t; blk < 1024; blk += 256) {
        S += psum[co*4096 + blk];
        Q += psq [co*4096 + blk];
    }
    #pragma unroll
    for (int off = 32; off > 0; off >>= 1) {
        S += __shfl_down(S, off, 64);
        Q += __shfl_down(Q, off, 64);
    }
    __shared__ float rs[4], rq[4];
    if ((t & 63) == 0) { rs[t >> 6] = S; rq[t >> 6] = Q; }
    __syncthreads();
    if (t == 0) {
        S = rs[0] + rs[1] + rs[2] + rs[3];
        Q = rq[0] + rq[1] + rq[2] + rq[3];
        const float cnt = 16.f * 63.f * 63.f * 63.f;
        const float mean = S / cnt;
        const float var  = Q / cnt - mean * mean;
        const float inv  = rsqrtf(var + 1e-5f);
        const float sc   = inv * gamma[co];
        bn[co]      = sc;
        bn[16 + co] = beta[co] - mean * sc;
    }
}

__global__ void finalize(const float* __restrict__ pooled, const float* __restrict__ bn,
                         float* __restrict__ out)
{
    const int i  = blockIdx.x * 256 + threadIdx.x;   // 864000 = 3375*256
    const int co = (i / 3375) & 15;
    out[i] = pooled[i] * bn[co] + bn[16 + co];
}

extern "C" void kernel_launch(void* const* d_in, const int* in_sizes, int n_in,
                              void* d_out, int out_size, void* d_ws, size_t ws_size,
                              hipStream_t stream)
{
    const float* x     = (const float*)d_in[0];
    const float* w     = (const float*)d_in[1];
    const float* b     = (const float*)d_in[2];
    const float* gamma = (const float*)d_in[3];
    const float* beta  = (const float*)d_in[4];
    float* out = (float*)d_out;

    char* wsb = (char*)d_ws;
    unsigned short* wT = (unsigned short*)wsb;        // 27,648 B
    float* pooled = (float*)(wsb + 27648);            // 3,456,000 B
    float* psum   = (float*)(wsb + 27648 + 3456000);  // 262,144 B
    float* psq    = (float*)(wsb + 27648 + 3456000 + 262144);
    float* bn     = (float*)(wsb + 27648 + 3456000 + 2*262144);

    kw<<<54, 256, 0, stream>>>(w, wT);
    dim3 grid(16, 16, 4);   // (ht, dt, n-quad)
    convf2<<<grid, 256, 0, stream>>>(x, wT, b, pooled, psum, psq);
    bnfinal<<<16, 256, 0, stream>>>(psum, psq, gamma, beta, bn);
    finalize<<<3375, 256, 0, stream>>>(pooled, bn, out);
}